// Round 9
// baseline (339.728 us; speedup 1.0000x reference)
//
#include <hip/hip_runtime.h>
#include <float.h>

#define ALPHA 0.2f
__device__ __forceinline__ float leakyf(float x) { return x > 0.0f ? x : ALPHA * x; }

__device__ __forceinline__ unsigned short f2bf(float f) {
    unsigned u = __float_as_uint(f);
    return (unsigned short)((u + 0x7FFFu + ((u >> 16) & 1u)) >> 16);
}
__device__ __forceinline__ float bflo(unsigned u) { return __uint_as_float(u << 16); }
__device__ __forceinline__ float bfhi(unsigned u) { return __uint_as_float(u & 0xFFFF0000u); }

typedef short bf16x8 __attribute__((ext_vector_type(8)));
typedef float f32x4 __attribute__((ext_vector_type(4)));

struct Ptr4i { const int* p0; const int* p1; const int* p2; const int* p3; };
struct PrepM { const float* W; const float* b; const float* attA; const float* attB; };

// ---------- prep: fragment-linear bf16 W (+ folded attention-dot cols) + bcnt zero ----------
__global__ __launch_bounds__(256) void prep_kernel(
    PrepM m0, PrepM m1, PrepM m2, PrepM m3, PrepM m4, PrepM m5,
    bf16x8* __restrict__ wfrag, float* __restrict__ cd,
    int* __restrict__ bcnt, int nz)
{
    int mi = blockIdx.x;
    PrepM mm = (mi == 0) ? m0 : (mi == 1) ? m1 : (mi == 2) ? m2 :
               (mi == 3) ? m3 : (mi == 4) ? m4 : m5;
    int part = blockIdx.y;
    if (mi == 0 && part == 0) {
        for (int i = threadIdx.x; i < nz; i += 256) bcnt[i] = 0;
    }
    for (int ii = 0; ii < 3; ++ii) {
        int c = part * 576 + threadIdx.x + 256 * ii;
        if (c >= part * 576 + 576) continue;
        int t = c >> 8;
        int kstep = (c >> 6) & 3;
        int l = c & 63;
        int k0 = kstep * 32 + (l >> 4) * 8;
        bf16x8 out;
        if (t < 8) {
            int col = t * 16 + (l & 15);
            #pragma unroll
            for (int j = 0; j < 8; ++j)
                out[j] = (short)f2bf(mm.W[(size_t)(k0 + j) * 128 + col]);
        } else {
            int cl = l & 15;
            const float* att = nullptr; int h = 0;
            if (cl < 4 && mm.attA) { att = mm.attA; h = cl; }
            else if (cl >= 4 && cl < 8 && mm.attB) { att = mm.attB; h = cl - 4; }
            #pragma unroll
            for (int j = 0; j < 8; ++j) {
                float s = 0.f;
                if (att) {
                    const float* wrow = mm.W + (size_t)(k0 + j) * 128 + h * 32;
                    for (int d = 0; d < 32; ++d) s += wrow[d] * att[h * 32 + d];
                }
                out[j] = (short)f2bf(s);
            }
        }
        wfrag[(size_t)mi * 2304 + c] = out;
    }
    if (part == 0 && threadIdx.x < 8) {
        int cl = threadIdx.x;
        float s = 0.f;
        const float* att = nullptr; int h = 0;
        if (cl < 4 && mm.attA) { att = mm.attA; h = cl; }
        else if (cl >= 4 && mm.attB) { att = mm.attB; h = cl - 4; }
        if (att) for (int d = 0; d < 32; ++d) s += mm.b[h * 32 + d] * att[h * 32 + d];
        cd[mi * 8 + cl] = s;
    }
}

// ---------- MFMA compute + epilogue for one matrix ----------
__device__ __forceinline__ void mfma_compute_store(
    const short* xs_s, const short* wl_s, int row0, int N,
    const float* __restrict__ b, float* __restrict__ o32, unsigned short* __restrict__ o16,
    float* __restrict__ dotA, float* __restrict__ dotB, const float* __restrict__ cd)
{
    int l = threadIdx.x & 63, w = threadIdx.x >> 6;
    int cl = l & 15, gq = l >> 4;
    f32x4 acc[9];
    #pragma unroll
    for (int t = 0; t < 9; ++t) acc[t] = (f32x4){0.f, 0.f, 0.f, 0.f};
    int arow = w * 16 + cl;
    #pragma unroll
    for (int ks = 0; ks < 4; ++ks) {
        int k8 = ks * 4 + gq;
        bf16x8 a = *(const bf16x8*)((const char*)xs_s + arow * 256 + ((k8 * 16) ^ ((arow & 7) << 4)));
        #pragma unroll
        for (int t = 0; t < 9; ++t) {
            bf16x8 bf = *(const bf16x8*)((const char*)wl_s + ((t * 4 + ks) * 64 + l) * 16);
            acc[t] = __builtin_amdgcn_mfma_f32_16x16x32_bf16(a, bf, acc[t], 0, 0, 0);
        }
    }
    int rbase = row0 + w * 16 + gq * 4;
    #pragma unroll
    for (int t = 0; t < 8; ++t) {
        int col = t * 16 + cl;
        float bias = b[col];
        #pragma unroll
        for (int j = 0; j < 4; ++j) {
            int row = rbase + j;
            if (row < N) {
                float v = acc[t][j] + bias;
                if (o32) o32[(size_t)row * 128 + col] = v;
                else     o16[(size_t)row * 128 + col] = f2bf(v);
            }
        }
    }
    if (cl < 8) {
        float cdv = cd[cl];
        float* dp = (cl < 4) ? dotA : dotB;
        int h = cl & 3;
        if (dp) {
            #pragma unroll
            for (int j = 0; j < 4; ++j) {
                int row = rbase + j;
                if (row < N) dp[(size_t)row * 4 + h] = acc[8][j] + cdv;
            }
        }
    }
}

struct Lin3Cfg {
    const float* x; int N; int blocks;
    const bf16x8* wfrag; const float* cd;
    const float* b0; float* o0; float* dA0; float* dB0;
    const float* b1; unsigned short* o1; float* dA1;
    const float* b2; unsigned short* o2; float* dA2;
};

// ---------- merged fused 3-matrix MFMA linear (P and A in one dispatch) ----------
__global__ __launch_bounds__(256) void lin3_mfma_kernel(Lin3Cfg cP, Lin3Cfg cA)
{
    __shared__ short xs_s[64 * 128];
    __shared__ short wl_s[2304 * 8];
    const bool isP = blockIdx.x < (unsigned)cP.blocks;
    const Lin3Cfg& c = isP ? cP : cA;
    const int bx = isP ? blockIdx.x : (blockIdx.x - cP.blocks);
    const int row0 = bx * 64;
    const int N = c.N;

    #pragma unroll
    for (int ii = 0; ii < 4; ++ii) {
        int ci = threadIdx.x + 256 * ii;
        int r = ci >> 4, k8 = ci & 15;
        int srcrow = row0 + r; if (srcrow >= N) srcrow = N - 1;
        const float4* gp = (const float4*)(c.x + (size_t)srcrow * 128 + k8 * 8);
        float4 v0 = gp[0], v1 = gp[1];
        bf16x8 p;
        p[0] = (short)f2bf(v0.x); p[1] = (short)f2bf(v0.y);
        p[2] = (short)f2bf(v0.z); p[3] = (short)f2bf(v0.w);
        p[4] = (short)f2bf(v1.x); p[5] = (short)f2bf(v1.y);
        p[6] = (short)f2bf(v1.z); p[7] = (short)f2bf(v1.w);
        *(bf16x8*)((char*)xs_s + r * 256 + ((k8 * 16) ^ ((r & 7) << 4))) = p;
    }
    #pragma unroll
    for (int ii = 0; ii < 9; ++ii)
        ((bf16x8*)wl_s)[threadIdx.x + 256 * ii] = c.wfrag[threadIdx.x + 256 * ii];
    __syncthreads();
    mfma_compute_store(xs_s, wl_s, row0, N, c.b0, c.o0, nullptr, c.dA0, c.dB0, c.cd);

    __syncthreads();
    #pragma unroll
    for (int ii = 0; ii < 9; ++ii)
        ((bf16x8*)wl_s)[threadIdx.x + 256 * ii] = c.wfrag[2304 + threadIdx.x + 256 * ii];
    __syncthreads();
    mfma_compute_store(xs_s, wl_s, row0, N, c.b1, nullptr, c.o1, c.dA1, nullptr, c.cd + 8);

    __syncthreads();
    #pragma unroll
    for (int ii = 0; ii < 9; ++ii)
        ((bf16x8*)wl_s)[threadIdx.x + 256 * ii] = c.wfrag[2 * 2304 + threadIdx.x + 256 * ii];
    __syncthreads();
    mfma_compute_store(xs_s, wl_s, row0, N, c.b2, nullptr, c.o2, c.dA2, nullptr, c.cd + 16);
}

// ================= bucketed CSR build (buckets of 1024 dsts) =================

// ---- pass A1: per-bucket edge counts (per-wave LDS histograms) ----
__global__ __launch_bounds__(256) void binA_count_kernel(Ptr4i dsts, int* __restrict__ bcnt,
                                                         int nbkMax, int E)
{
    __shared__ int lh[4][128];
    ((int*)lh)[threadIdx.x] = 0;
    ((int*)lh)[threadIdx.x + 256] = 0;
    __syncthreads();
    int r = blockIdx.y;
    int w = threadIdx.x >> 6;
    const int* dst = (r == 0) ? dsts.p0 : (r == 1) ? dsts.p1 : (r == 2) ? dsts.p2 : dsts.p3;
    int base = blockIdx.x * 4096;
    #pragma unroll 4
    for (int ii = 0; ii < 16; ++ii) {
        int i = base + threadIdx.x + 256 * ii;
        if (i < E) atomicAdd(&lh[w][dst[i] >> 10], 1);
    }
    __syncthreads();
    if (threadIdx.x < 128) {
        int v = lh[0][threadIdx.x] + lh[1][threadIdx.x] + lh[2][threadIdx.x] + lh[3][threadIdx.x];
        if (v && threadIdx.x < nbkMax) atomicAdd(&bcnt[r * nbkMax + threadIdx.x], v);
    }
}

// ---- parallel scan of bucket counts (4 relations x 128 lanes, one block) ----
__global__ __launch_bounds__(512) void bin_scan_kernel(const int* __restrict__ bcnt,
                                                       int* __restrict__ bbase,
                                                       int* __restrict__ gwptr, int nbkMax)
{
    __shared__ int sh[4][128];
    int r = threadIdx.x >> 7, b = threadIdx.x & 127;
    int v = (b < nbkMax) ? bcnt[r * nbkMax + b] : 0;
    sh[r][b] = v;
    __syncthreads();
    #pragma unroll
    for (int off = 1; off < 128; off <<= 1) {
        int y = (b >= off) ? sh[r][b - off] : 0;
        __syncthreads();
        sh[r][b] += y;
        __syncthreads();
    }
    if (b < nbkMax) {
        int ex = sh[r][b] - v;
        bbase[r * nbkMax + b] = ex;
        gwptr[r * nbkMax + b] = ex;
    }
}

// ---- pass A2: LDS-binned scatter into bucket-ordered packed array ----
__global__ __launch_bounds__(256) void binA_scatter_kernel(Ptr4i dsts, Ptr4i srcs,
    int* __restrict__ gwptr, unsigned* __restrict__ packed, int nbkMax, int E)
{
    __shared__ int lh[128], loff[128], lptr[128], gb[128];
    __shared__ unsigned stg[4096];
    __shared__ unsigned short sb[4096];
    if (threadIdx.x < 128) lh[threadIdx.x] = 0;
    __syncthreads();
    int r = blockIdx.y;
    const int* dst = (r == 0) ? dsts.p0 : (r == 1) ? dsts.p1 : (r == 2) ? dsts.p2 : dsts.p3;
    const int* src = (r == 0) ? srcs.p0 : (r == 1) ? srcs.p1 : (r == 2) ? srcs.p2 : srcs.p3;
    int base = blockIdx.x * 4096;
    int d16[16], s16[16];
    #pragma unroll 4
    for (int ii = 0; ii < 16; ++ii) {
        int i = base + threadIdx.x + 256 * ii;
        if (i < E) {
            d16[ii] = dst[i];
            s16[ii] = src[i];
            atomicAdd(&lh[d16[ii] >> 10], 1);
        } else d16[ii] = -1;
    }
    __syncthreads();
    if (threadIdx.x == 0) {
        int run = 0;
        for (int b = 0; b < nbkMax; ++b) { loff[b] = run; lptr[b] = run; run += lh[b]; }
    }
    __syncthreads();
    #pragma unroll 4
    for (int ii = 0; ii < 16; ++ii) {
        if (d16[ii] >= 0) {
            int b = d16[ii] >> 10;
            int p = atomicAdd(&lptr[b], 1);
            stg[p] = ((unsigned)s16[ii] << 10) | (unsigned)(d16[ii] & 1023);
            sb[p] = (unsigned short)b;
        }
    }
    __syncthreads();
    if (threadIdx.x < nbkMax && lh[threadIdx.x])
        gb[threadIdx.x] = atomicAdd(&gwptr[r * nbkMax + threadIdx.x], lh[threadIdx.x]);
    __syncthreads();
    int tot = min(4096, E - base);
    #pragma unroll 4
    for (int ii = 0; ii < 16; ++ii) {
        int p = threadIdx.x + 256 * ii;
        if (p < tot) {
            int b = sb[p];
            packed[(size_t)r * E + gb[b] + (p - loff[b])] = stg[p];
        }
    }
}

// ---- pass B: per-bucket CSR finalize ----
__global__ __launch_bounds__(256) void binB_build_kernel(
    const unsigned* __restrict__ packed, const int* __restrict__ bcnt, const int* __restrict__ bbase,
    int nbkMax, int4 Ns, int E, int stride,
    int* __restrict__ start, int* __restrict__ deg, int* __restrict__ csrc)
{
    int r = blockIdx.y, b = blockIdx.x;
    int N = (r == 0) ? Ns.x : (r == 1) ? Ns.y : (r == 2) ? Ns.z : Ns.w;
    int dst0 = b << 10;
    if (dst0 >= N) return;
    int cnt  = bcnt[r * nbkMax + b];
    int base = bbase[r * nbkMax + b];
    __shared__ int hist[1024];
    __shared__ int sums[256];
    #pragma unroll
    for (int i = 0; i < 4; ++i) hist[threadIdx.x * 4 + i] = 0;
    __syncthreads();
    const unsigned* pk = packed + (size_t)r * E + base;
    for (int i = threadIdx.x; i < cnt; i += 256)
        atomicAdd(&hist[pk[i] & 1023], 1);
    __syncthreads();
    int v4[4], s = 0;
    #pragma unroll
    for (int i = 0; i < 4; ++i) { v4[i] = hist[threadIdx.x * 4 + i]; s += v4[i]; }
    sums[threadIdx.x] = s;
    __syncthreads();
    #pragma unroll
    for (int off = 1; off < 256; off <<= 1) {
        int y = (threadIdx.x >= off) ? sums[threadIdx.x - off] : 0;
        __syncthreads();
        sums[threadIdx.x] += y;
        __syncthreads();
    }
    int run = sums[threadIdx.x] - s;
    int* st = start + (size_t)r * stride;
    int* dg = deg   + (size_t)r * stride;
    #pragma unroll
    for (int i = 0; i < 4; ++i) {
        int idx = threadIdx.x * 4 + i;
        int d = dst0 + idx;
        if (d < N) { dg[d] = v4[i]; st[d] = base + run; }
        hist[idx] = run;
        run += v4[i];
    }
    __syncthreads();
    int* cs = csrc + (size_t)r * E + base;
    for (int i = threadIdx.x; i < cnt; i += 256) {
        unsigned e = pk[i];
        int p = atomicAdd(&hist[e & 1023], 1);
        cs[p] = (int)(e >> 10);
    }
}

// ---------- merged per-dst fused GAT: 8 lanes/edge x 8 edge slots ----------
struct GatRel {
    const int* start; const int* deg; const int* csrc;
    const unsigned short* Wh; const float* es; const float* ed;
};
struct GatCfg { float* out; int Nd; int blocks; GatRel rel0, rel1; };

__global__ __launch_bounds__(256) void gat_node_kernel(GatCfg cP, GatCfg cA)
{
    const bool isP = blockIdx.x < (unsigned)cP.blocks;
    const GatCfg& c = isP ? cP : cA;
    const int bx = isP ? blockIdx.x : (blockIdx.x - cP.blocks);
    int gid = bx * 256 + threadIdx.x;
    int d = gid >> 6;
    if (d >= c.Nd) return;
    int lane = threadIdx.x & 63;
    int q = lane >> 3;        // edge slot 0..7
    int l = lane & 7;         // dim group: dims 16l..16l+15
    int h = l >> 1;           // head

    // per-slot partial message accumulators (scaled per relation, reduced once at end)
    float4 A0 = {0.f, 0.f, 0.f, 0.f}, A1 = A0, A2 = A0, A3 = A0;

    #pragma unroll
    for (int rel = 0; rel < 2; ++rel) {
        const GatRel& R = rel ? c.rel1 : c.rel0;
        int st = R.start[d];
        int n  = R.deg[d];
        if (n == 0) continue;
        const uint4* W4 = (const uint4*)R.Wh;   // row = 128 bf16 = 16 uint4
        float edv = R.ed[(size_t)d * 4 + h];
        float sum = 0.f;
        float4 M0 = {0.f, 0.f, 0.f, 0.f}, M1 = M0, M2 = M0, M3 = M0;
        for (int j = q; j < n; j += 8) {
            int s = R.csrc[st + j];
            float p = __expf(leakyf(R.es[(size_t)s * 4 + h] + edv));
            const uint4* wp = W4 + (size_t)s * 16 + l * 2;
            uint4 w0 = wp[0], w1 = wp[1];
            sum += p;
            M0.x += p * bflo(w0.x); M0.y += p * bfhi(w0.x);
            M0.z += p * bflo(w0.y); M0.w += p * bfhi(w0.y);
            M1.x += p * bflo(w0.z); M1.y += p * bfhi(w0.z);
            M1.z += p * bflo(w0.w); M1.w += p * bfhi(w0.w);
            M2.x += p * bflo(w1.x); M2.y += p * bfhi(w1.x);
            M2.z += p * bflo(w1.y); M2.w += p * bfhi(w1.y);
            M3.x += p * bflo(w1.z); M3.y += p * bfhi(w1.z);
            M3.z += p * bflo(w1.w); M3.w += p * bfhi(w1.w);
        }
        // reduce only the softmax denominator across the 8 slots
        sum += __shfl_xor(sum, 8, 64);
        sum += __shfl_xor(sum, 16, 64);
        sum += __shfl_xor(sum, 32, 64);
        float inv = 1.0f / sum;
        A0.x += M0.x * inv; A0.y += M0.y * inv; A0.z += M0.z * inv; A0.w += M0.w * inv;
        A1.x += M1.x * inv; A1.y += M1.y * inv; A1.z += M1.z * inv; A1.w += M1.w * inv;
        A2.x += M2.x * inv; A2.y += M2.y * inv; A2.z += M2.z * inv; A2.w += M2.w * inv;
        A3.x += M3.x * inv; A3.y += M3.y * inv; A3.z += M3.z * inv; A3.w += M3.w * inv;
    }
    // single final reduce of the 16 accumulated dims across slots
    #pragma unroll
    for (int off = 8; off < 64; off <<= 1) {
        A0.x += __shfl_xor(A0.x, off, 64); A0.y += __shfl_xor(A0.y, off, 64);
        A0.z += __shfl_xor(A0.z, off, 64); A0.w += __shfl_xor(A0.w, off, 64);
        A1.x += __shfl_xor(A1.x, off, 64); A1.y += __shfl_xor(A1.y, off, 64);
        A1.z += __shfl_xor(A1.z, off, 64); A1.w += __shfl_xor(A1.w, off, 64);
        A2.x += __shfl_xor(A2.x, off, 64); A2.y += __shfl_xor(A2.y, off, 64);
        A2.z += __shfl_xor(A2.z, off, 64); A2.w += __shfl_xor(A2.w, off, 64);
        A3.x += __shfl_xor(A3.x, off, 64); A3.y += __shfl_xor(A3.y, off, 64);
        A3.z += __shfl_xor(A3.z, off, 64); A3.w += __shfl_xor(A3.w, off, 64);
    }
    if (lane < 8) {
        float4* ow = (float4*)(c.out + (size_t)d * 128 + l * 16);
        float4 s0 = ow[0], s1 = ow[1], s2 = ow[2], s3 = ow[3];
        s0.x = fmaxf(s0.x + A0.x, 0.f); s0.y = fmaxf(s0.y + A0.y, 0.f);
        s0.z = fmaxf(s0.z + A0.z, 0.f); s0.w = fmaxf(s0.w + A0.w, 0.f);
        s1.x = fmaxf(s1.x + A1.x, 0.f); s1.y = fmaxf(s1.y + A1.y, 0.f);
        s1.z = fmaxf(s1.z + A1.z, 0.f); s1.w = fmaxf(s1.w + A1.w, 0.f);
        s2.x = fmaxf(s2.x + A2.x, 0.f); s2.y = fmaxf(s2.y + A2.y, 0.f);
        s2.z = fmaxf(s2.z + A2.z, 0.f); s2.w = fmaxf(s2.w + A2.w, 0.f);
        s3.x = fmaxf(s3.x + A3.x, 0.f); s3.y = fmaxf(s3.y + A3.y, 0.f);
        s3.z = fmaxf(s3.z + A3.z, 0.f); s3.w = fmaxf(s3.w + A3.w, 0.f);
        ow[0] = s0; ow[1] = s1; ow[2] = s2; ow[3] = s3;
    }
}

extern "C" void kernel_launch(void* const* d_in, const int* in_sizes, int n_in,
                              void* d_out, int out_size, void* d_ws, size_t ws_size,
                              hipStream_t stream)
{
    const float* feat_P = (const float*)d_in[0];
    const float* feat_A = (const float*)d_in[1];
    const int* src_p2p = (const int*)d_in[2];
    const int* dst_p2p = (const int*)d_in[3];
    const int* src_p2a = (const int*)d_in[4];
    const int* dst_p2a = (const int*)d_in[5];
    const int* src_a2p = (const int*)d_in[6];
    const int* dst_a2p = (const int*)d_in[7];
    const int* src_a2a = (const int*)d_in[8];
    const int* dst_a2a = (const int*)d_in[9];
    const float* W_P   = (const float*)d_in[10]; const float* b_P   = (const float*)d_in[11];
    const float* W_A   = (const float*)d_in[12]; const float* b_A   = (const float*)d_in[13];
    const float* W_p2p = (const float*)d_in[14]; const float* b_p2p = (const float*)d_in[15];
    const float* W_p2a = (const float*)d_in[16]; const float* b_p2a = (const float*)d_in[17];
    const float* W_a2p = (const float*)d_in[18]; const float* b_a2p = (const float*)d_in[19];
    const float* W_a2a = (const float*)d_in[20]; const float* b_a2a = (const float*)d_in[21];
    const float* att_p2p_src = (const float*)d_in[22];
    const float* att_p2p_dst = (const float*)d_in[23];
    const float* att_p2a_src = (const float*)d_in[24];
    const float* att_p2a_dst = (const float*)d_in[25];
    const float* att_a2p_src = (const float*)d_in[26];
    const float* att_a2p_dst = (const float*)d_in[27];
    const float* att_a2a_src = (const float*)d_in[28];
    const float* att_a2a_dst = (const float*)d_in[29];

    const int NP = in_sizes[0] / 128;
    const int NA = in_sizes[1] / 128;
    const int E  = in_sizes[2];
    const int stride = (NP > NA) ? NP : NA;
    const int nbkMax = (stride + 1023) >> 10;   // <= 128

    float* outP = (float*)d_out;
    float* outA = (float*)d_out + (size_t)NP * 128;

    char* ws = (char*)d_ws;
    size_t off = 0;
    auto alloc = [&](size_t bytes) -> void* {
        void* p = ws + off;
        off += (bytes + 255) & ~(size_t)255;
        return p;
    };
    unsigned short* Whp2p = (unsigned short*)alloc((size_t)NP * 128 * 2);
    unsigned short* Whp2a = (unsigned short*)alloc((size_t)NP * 128 * 2);
    unsigned short* Wha2p = (unsigned short*)alloc((size_t)NA * 128 * 2);
    unsigned short* Wha2a = (unsigned short*)alloc((size_t)NA * 128 * 2);
    float* es_p2p = (float*)alloc((size_t)NP * 16);
    float* es_p2a = (float*)alloc((size_t)NP * 16);
    float* es_a2p = (float*)alloc((size_t)NA * 16);
    float* es_a2a = (float*)alloc((size_t)NA * 16);
    float* ed_p2p = (float*)alloc((size_t)NP * 16);
    float* ed_a2p = (float*)alloc((size_t)NP * 16);
    float* ed_p2a = (float*)alloc((size_t)NA * 16);
    float* ed_a2a = (float*)alloc((size_t)NA * 16);
    int* deg    = (int*)alloc((size_t)4 * stride * 4);
    int* start  = (int*)alloc((size_t)4 * stride * 4);
    int* csrc   = (int*)alloc((size_t)4 * E * 4);
    unsigned* packed = (unsigned*)alloc((size_t)4 * E * 4);
    int* bcnt   = (int*)alloc((size_t)4 * nbkMax * 4);
    int* bbase  = (int*)alloc((size_t)4 * nbkMax * 4);
    int* gwptr  = (int*)alloc((size_t)4 * nbkMax * 4);
    bf16x8* wfrag = (bf16x8*)alloc((size_t)6 * 2304 * 16);
    float* cd     = (float*)alloc((size_t)6 * 8 * 4);

    // relation order: 0=p2p(dst P), 1=a2p(dst P), 2=p2a(dst A), 3=a2a(dst A)
    Ptr4i dsts = {dst_p2p, dst_a2p, dst_p2a, dst_a2a};
    Ptr4i srcs = {src_p2p, src_a2p, src_p2a, src_a2a};
    int4 Ns = make_int4(NP, NP, NA, NA);

    // ---- 0) prep weights (+ zero bcnt) ----
    {
        PrepM m0 = {W_P,   b_P,   att_p2p_dst, att_a2p_dst};
        PrepM m1 = {W_p2p, b_p2p, att_p2p_src, nullptr};
        PrepM m2 = {W_p2a, b_p2a, att_p2a_src, nullptr};
        PrepM m3 = {W_A,   b_A,   att_p2a_dst, att_a2a_dst};
        PrepM m4 = {W_a2p, b_a2p, att_a2p_src, nullptr};
        PrepM m5 = {W_a2a, b_a2a, att_a2a_src, nullptr};
        prep_kernel<<<dim3(6, 4), 256, 0, stream>>>(m0, m1, m2, m3, m4, m5, wfrag, cd,
                                                    bcnt, 4 * nbkMax);
    }

    // ---- 1) merged MFMA linears ----
    {
        Lin3Cfg cP = {feat_P, NP, (NP + 63) / 64, wfrag, cd,
                      b_P, outP, ed_p2p, ed_a2p,
                      b_p2p, Whp2p, es_p2p,
                      b_p2a, Whp2a, es_p2a};
        Lin3Cfg cA = {feat_A, NA, (NA + 63) / 64, wfrag + (size_t)3 * 2304, cd + 24,
                      b_A, outA, ed_p2a, ed_a2a,
                      b_a2p, Wha2p, es_a2p,
                      b_a2a, Wha2a, es_a2a};
        lin3_mfma_kernel<<<cP.blocks + cA.blocks, 256, 0, stream>>>(cP, cA);
    }

    // ---- 2) bucketed CSR build ----
    {
        dim3 gA((E + 4095) / 4096, 4);
        binA_count_kernel<<<gA, 256, 0, stream>>>(dsts, bcnt, nbkMax, E);
        bin_scan_kernel<<<1, 512, 0, stream>>>(bcnt, bbase, gwptr, nbkMax);
        binA_scatter_kernel<<<gA, 256, 0, stream>>>(dsts, srcs, gwptr, packed, nbkMax, E);
        binB_build_kernel<<<dim3(nbkMax, 4), 256, 0, stream>>>(packed, bcnt, bbase,
            nbkMax, Ns, E, stride, start, deg, csrc);
    }

    // ---- 3) merged per-dst aggregation (+self +relu) ----
    {
        GatCfg cP = {outP, NP, (NP * 64 + 255) / 256,
            {start + 0 * (size_t)stride, deg + 0 * (size_t)stride, csrc + 0 * (size_t)E, Whp2p, es_p2p, ed_p2p},
            {start + 1 * (size_t)stride, deg + 1 * (size_t)stride, csrc + 1 * (size_t)E, Wha2p, es_a2p, ed_a2p}};
        GatCfg cA = {outA, NA, (NA * 64 + 255) / 256,
            {start + 2 * (size_t)stride, deg + 2 * (size_t)stride, csrc + 2 * (size_t)E, Whp2a, es_p2a, ed_p2a},
            {start + 3 * (size_t)stride, deg + 3 * (size_t)stride, csrc + 3 * (size_t)E, Wha2a, es_a2a, ed_a2a}};
        gat_node_kernel<<<cP.blocks + cA.blocks, 256, 0, stream>>>(cP, cA);
    }
}